// Round 16
// baseline (291.525 us; speedup 1.0000x reference)
//
#include <hip/hip_runtime.h>

typedef unsigned short u16;
typedef unsigned int   u32;
typedef __attribute__((ext_vector_type(8)))  __bf16 bf16x8;
typedef __attribute__((ext_vector_type(4)))  float  f32x4;
typedef __attribute__((ext_vector_type(16))) float  f32x16;
typedef __attribute__((ext_vector_type(4)))  u32    u32x4;
typedef __attribute__((ext_vector_type(2)))  u32    u32x2;

#define F_DIM   1152
#define QKV_DIM 3456
#define HD_SCALE 0.083333333333333333f   // 1/sqrt(144)
#define LOG2E    1.4426950408889634f
#define KSC      (HD_SCALE*LOG2E)        // folded score scale (log2 domain)
#define MAX4    80                        // >= sum ceil(ntg/4) over graphs
#define PREP_BLKS 4096

static __device__ __forceinline__ u16 f2bf(float f){
    u32 u = __builtin_bit_cast(u32, f);
    u32 r = u + 0x7fffu + ((u >> 16) & 1u);   // RNE
    return (u16)(r >> 16);
}
static __device__ __forceinline__ u32 cvtpk(float lo, float hi){
    u32 r;
    asm("v_cvt_pk_bf16_f32 %0, %1, %2" : "=v"(r) : "v"(lo), "v"(hi));
    return r;
}

typedef __attribute__((address_space(1))) void gvoid;
typedef __attribute__((address_space(3))) void lvoid;
static __device__ __forceinline__ void gload16(const u16* g, u16* l){
    __builtin_amdgcn_global_load_lds((gvoid*)g, (lvoid*)l, 16, 0, 0);
}

// ---------------------------------------------------------------------------
// prep_kernel v16 — HYBRID blocks: each of 4096 blocks grid-strides over BOTH
// the bias-block list (VALU-bound) and the memory-unit list (cast/transpose/
// meta, memory-bound), with parity-alternated phase order so half the
// resident waves are VALU-issuing while half are memory-issuing (m114-style
// pipe overlap), and per-block durations stay uniform (no r13 tail).
// Bias stored *LOG2E, PERMUTED: biasP[bb*8192 + h*1024 + i*32 + c],
// j = (c&3) + ((c>>2)&3)*8 + (c>>4)*4.
// mem units: [0,9216) cast (256 float4), [9216,14400) W transposes, 14400 meta.
// ---------------------------------------------------------------------------
__global__ __launch_bounds__(256) void prep_kernel(
        const float* __restrict__ x, u16* __restrict__ xb, int nCast, int n4,
        const float* __restrict__ Wqkv, u16* __restrict__ wqkvT,
        const float* __restrict__ Wout, u16* __restrict__ woutT,
        const float* __restrict__ pos, const float* __restrict__ rfreq,
        const float* __restrict__ Wrope, u16* __restrict__ biasP,
        const int* __restrict__ batch, int* __restrict__ meta, int N){
    __shared__ float tile[32][33];
    __shared__ int goffs[17];
    __shared__ int bpre[17];
    const int b = blockIdx.x, t = threadIdx.x;
    const int T1 = (QKV_DIM/32)*(F_DIM/32);   // 3888
    const int T2 = (F_DIM/32)*(F_DIM/32);     // 1296
    const int NMEM = nCast + T1 + T2 + 1;     // 14401

    // graph layout (all blocks; cheap)
    if (t <= 16){
        int lo = 0, hi = N;
        while (lo < hi){ int mid = (lo+hi)>>1; if (batch[mid] < t) lo = mid+1; else hi = mid; }
        goffs[t] = lo;
    }
    __syncthreads();
    if (t == 0){
        int bc = 0;
        for (int g = 0; g < 16; g++){
            bpre[g] = bc;
            int ng = goffs[g+1] - goffs[g];
            int ntg = (ng + 31) >> 5;
            bc += ntg*ntg;
        }
        bpre[16] = bc;
    }
    __syncthreads();

    auto do_bias = [&](){
        float absf[16], w[16][8];
        #pragma unroll
        for (int r = 0; r < 16; r++){
            absf[r] = fabsf(rfreq[r]);
            #pragma unroll
            for (int h = 0; h < 8; h++) w[r][h] = Wrope[r*8 + h] * LOG2E;
        }
        const int total = bpre[16];
        for (int bb = b; bb < total; bb += PREP_BLKS){
            int g = 0;
            while (bpre[g+1] <= bb) g++;
            int rem  = bb - bpre[g];
            int goff = goffs[g];
            int ng   = goffs[g+1] - goff;
            int ntg  = (ng + 31) >> 5;
            int qt   = rem / ntg;
            int jt   = rem - qt*ntg;
            size_t base = (size_t)bb * 8192;
            #pragma unroll
            for (int pp = 0; pp < 2; pp++){
                const int p0 = pp*512 + 2*t;          // even; p0,p0+1 share i
                float bv0[8], bv1[8];
                #pragma unroll
                for (int h = 0; h < 8; h++){ bv0[h] = 0.f; bv1[h] = 0.f; }
                const int i = p0 >> 5;
                int qn = goff + qt*32 + i;  if (qn >= goff + ng) qn = goff + ng - 1;
                float qx = pos[qn*3+0], qy = pos[qn*3+1], qz = pos[qn*3+2];
                #pragma unroll
                for (int e = 0; e < 2; e++){
                    int c = (p0 + e) & 31;
                    int p4 = c & 15;
                    int j  = (p4 & 3) + ((p4 >> 2) << 3) + ((c >> 4) << 2);
                    int kn = goff + jt*32 + j;  if (kn >= goff + ng) kn = goff + ng - 1;
                    float dx = qx - pos[kn*3+0];
                    float dy = qy - pos[kn*3+1];
                    float dz = qz - pos[kn*3+2];
                    float d  = sqrtf(dx*dx + dy*dy + dz*dz);
                    float* bv = e ? bv1 : bv0;
                    #pragma unroll
                    for (int r = 0; r < 16; r++){
                        float cs = __cosf(d * absf[r]);
                        #pragma unroll
                        for (int h = 0; h < 8; h++) bv[h] = fmaf(cs, w[r][h], bv[h]);
                    }
                }
                #pragma unroll
                for (int h = 0; h < 8; h++)
                    *(u32*)&biasP[base + h*1024 + p0] = cvtpk(bv0[h], bv1[h]);
            }
        }
    };

    auto do_mem = [&](){
        for (int u = b; u < NMEM; u += PREP_BLKS){
            if (u < nCast){
                int i = u*256 + t;
                if (i < n4){
                    float4 v = ((const float4*)x)[i];
                    u32x2 o; o[0] = cvtpk(v.x, v.y); o[1] = cvtpk(v.z, v.w);
                    *(u32x2*)&xb[(size_t)i*4] = o;
                }
            } else if (u < nCast + T1 + T2){
                const float* in; u16* out; int R, C, bi;
                if (u < nCast + T1){ in = Wqkv; out = wqkvT; R = F_DIM; C = QKV_DIM; bi = u - nCast; }
                else               { in = Wout; out = woutT; R = F_DIM; C = F_DIM;  bi = u - nCast - T1; }
                int gx = C/32;
                int c0 = (bi % gx)*32, r0 = (bi / gx)*32;
                int tx = t & 31, ty = t >> 5;
                __syncthreads();               // protect tile reuse across units
                #pragma unroll
                for (int yy = ty; yy < 32; yy += 8)
                    tile[yy][tx] = in[(size_t)(r0+yy)*C + (c0+tx)];
                __syncthreads();
                #pragma unroll
                for (int yy = ty; yy < 32; yy += 8)
                    out[(size_t)(c0+yy)*R + (r0+tx)] = f2bf(tile[tx][yy]);
            } else {
                // ---- meta (one unit) ----
                if (t <= 16) meta[1+t] = goffs[t];
                __syncthreads();
                if (t == 0){
                    int ps = 0, bcnt = 0, cnt4 = 0;
                    for (int g = 0; g < 16; g++){
                        int ng = meta[2+g] - meta[1+g];
                        meta[20+g] = ps;
                        meta[40+g] = bcnt;
                        int nt = (ng + 31) / 32;
                        ps += nt * 32;
                        bcnt += nt * nt;
                        int nt4 = (nt + 3) / 4;
                        for (int q4 = 0; q4 < nt4; q4++){
                            meta[64 + cnt4] = g;
                            meta[64 + MAX4 + cnt4] = q4;
                            cnt4++;
                        }
                    }
                    meta[36] = ps;
                    meta[56] = bcnt;
                    meta[0]  = cnt4;
                }
            }
        }
    };

    if (b & 1){ do_bias(); do_mem(); }
    else      { do_mem(); do_bias(); }
}

// ---------------------------------------------------------------------------
// gemm256 (round-12 v1): C[M,Ncols] = A[M,K]*Bt[Ncols,K]^T.
// 256x256 tile, 512 thr (8 waves 2Mx4N), BK=32, 4-deep LDS pipeline:
//   iter t: STAGE(t+2) -> s_waitcnt vmcnt(8)+s_barrier -> ds_read -> 32 MFMA.
// vmcnt never drains to 0 (T4); one barrier/K-step. T2 chunk-XOR swizzle via
// pre-swizzled source; T1 XCD swizzle; T5 setprio.
// ---------------------------------------------------------------------------
template<bool OUT_BF16>
__global__ __launch_bounds__(512, 2) void gemm256(const u16* __restrict__ A,
                                                  const u16* __restrict__ Bt,
                                                  void* __restrict__ Cp,
                                                  int M, int Ncols, int K){
    __shared__ u16 sA[4][8192];
    __shared__ u16 sB[4][8192];
    const int nwg = gridDim.x;
    int orig = blockIdx.x;
    int qq = nwg >> 3, rr = nwg & 7;
    int xcd = orig & 7, pos = orig >> 3;
    int nid = (xcd < rr ? xcd*(qq+1) : rr*(qq+1) + (xcd-rr)*qq) + pos;
    const int gx = M >> 8;
    const int bm = (nid % gx) << 8, bn = (nid / gx) << 8;

    const int tid = threadIdx.x;
    const int w = tid >> 6, lane = tid & 63;
    const int wr = w >> 2, wc = w & 3;
    const int fr = lane & 15, fq = lane >> 4;
    const int swz8 = (fq ^ ((fr >> 1) & 3)) * 8;

    const u16* aS[2]; const u16* bS[2]; int dOf[2];
    #pragma unroll
    for (int p = 0; p < 2; p++){
        int idx = p*512 + tid;
        int row = idx >> 2, c = idx & 3;
        int sc = c ^ ((row >> 1) & 3);
        int brow = bn + row; if (brow > Ncols-1) brow = Ncols-1;
        aS[p] = A  + (size_t)(bm + row)*K + sc*8;
        bS[p] = Bt + (size_t)brow*K + sc*8;
        dOf[p] = idx*8;
    }

    f32x4 acc[8][4];
    #pragma unroll
    for (int m = 0; m < 8; m++)
        #pragma unroll
        for (int n = 0; n < 4; n++)
            #pragma unroll
            for (int e = 0; e < 4; e++) acc[m][n][e] = 0.f;

    const int nk = K >> 5;
    #pragma unroll
    for (int p = 0; p < 2; p++){ gload16(aS[p], &sA[0][dOf[p]]); gload16(bS[p], &sB[0][dOf[p]]); }
    #pragma unroll
    for (int p = 0; p < 2; p++){ gload16(aS[p]+32, &sA[1][dOf[p]]); gload16(bS[p]+32, &sB[1][dOf[p]]); }

    #pragma unroll 1
    for (int t = 0; t < nk; t++){
        int tp = (t+2 < nk) ? t+2 : nk-1;
        int bufS = (t+2) & 3;
        #pragma unroll
        for (int p = 0; p < 2; p++){
            gload16(aS[p] + tp*32, &sA[bufS][dOf[p]]);
            gload16(bS[p] + tp*32, &sB[bufS][dOf[p]]);
        }
        asm volatile("s_waitcnt vmcnt(8)\n\ts_barrier" ::: "memory");

        const u16* sAc = &sA[t & 3][0];
        const u16* sBc = &sB[t & 3][0];
        bf16x8 af[8], bfr[4];
        #pragma unroll
        for (int m = 0; m < 8; m++)
            af[m] = *(const bf16x8*)(sAc + (wr*128 + m*16 + fr)*32 + swz8);
        #pragma unroll
        for (int n = 0; n < 4; n++)
            bfr[n] = *(const bf16x8*)(sBc + (wc*64 + n*16 + fr)*32 + swz8);
        __builtin_amdgcn_s_setprio(1);
        #pragma unroll
        for (int m = 0; m < 8; m++)
            #pragma unroll
            for (int n = 0; n < 4; n++)
                acc[m][n] = __builtin_amdgcn_mfma_f32_16x16x32_bf16(af[m], bfr[n], acc[m][n], 0, 0, 0);
        __builtin_amdgcn_s_setprio(0);
    }

    #pragma unroll
    for (int m = 0; m < 8; m++)
        #pragma unroll
        for (int n = 0; n < 4; n++)
            #pragma unroll
            for (int r = 0; r < 4; r++){
                int row = bm + wr*128 + m*16 + fq*4 + r;
                int col = bn + wc*64 + n*16 + fr;
                if (col < Ncols){
                    float v = acc[m][n][r];
                    if (OUT_BF16) ((u16*)Cp)[(size_t)row*Ncols + col] = f2bf(v);
                    else          ((float*)Cp)[(size_t)row*Ncols + col] = v;
                }
            }
}

// ---------------------------------------------------------------------------
// Vpack[h][ptile][d=144][key&31] = v[node][h*144+d] ; dense 9KB per KV tile.
// ---------------------------------------------------------------------------
__global__ __launch_bounds__(256) void pack_v(const u16* __restrict__ qkv,
                                              u16* __restrict__ Vpack,
                                              const int* __restrict__ batch,
                                              const int* __restrict__ meta,
                                              int PT){
    __shared__ u16 tile[32][33];
    int nt0 = blockIdx.x*32, dt0 = blockIdx.y*32, h = blockIdx.z;
    int tx = threadIdx.x & 31, ty = threadIdx.x >> 5;
    #pragma unroll
    for (int yy = ty; yy < 32; yy += 8){
        int node = nt0+yy, d = dt0+tx;
        tile[yy][tx] = (d < 144) ? qkv[(size_t)node*QKV_DIM + 2*F_DIM + h*144 + d] : (u16)0;
    }
    __syncthreads();
    int node = nt0 + tx;
    int g = batch[node];
    int col = meta[20+g] + (node - meta[1+g]);
    int pt = col >> 5, cl = col & 31;
    #pragma unroll
    for (int yy = ty; yy < 32; yy += 8){
        int d = dt0+yy;
        if (d < 144) Vpack[(((size_t)h*PT + pt)*144 + d)*32 + cl] = tile[tx][yy];
    }
}

// ---------------------------------------------------------------------------
// Flash attention: KVBLK=32, block = 4 waves = 4 q-tiles of one (graph,head).
// 38KB LDS -> 3 blocks/CU. No-max softmax, cvt_pk P-pack, setprio,
// reg-double-buffered bias (coalesced b128 from permuted table).
// ---------------------------------------------------------------------------
__global__ __launch_bounds__(256) void attn_kernel(
        const u16* __restrict__ qkv, const u16* __restrict__ Vpack,
        const u16* __restrict__ biasP, u16* __restrict__ attn_out,
        const int* __restrict__ meta, int PT){
    __shared__ u16 sK[2][4864];   // 32 rows x 304B (19 chunks, pad dup)
    __shared__ u16 sV[2][4608];   // [144][32] chunk-XOR swizzled
    const int h = blockIdx.x & 7, t4 = blockIdx.x >> 3;
    if (t4 >= meta[0]) return;
    const int g    = meta[64 + t4];
    const int q4   = meta[64 + MAX4 + t4];
    const int goff = meta[1+g], gend = meta[2+g];
    const int ng   = gend - goff;
    const int ntg  = (ng + 31) >> 5;
    const int pst  = meta[20+g];
    const int boffg= meta[40+g];

    const int tid = threadIdx.x;
    const int w = tid >> 6, lane = tid & 63;
    const int li = lane & 31, hi = lane >> 5;
    const int qt = q4*4 + w;
    const int qbase = goff + qt*32;
    const int qtP = (qt < ntg) ? qt : (ntg - 1);

    int kOff[3];
    #pragma unroll
    for (int p = 0; p < 3; p++){
        int idx = p*256 + tid;
        if (idx > 607) idx = 607;
        int row = idx/19, c = idx - row*19;
        if (c == 18) c = 0;
        kOff[p] = row*QKV_DIM + c*8;
    }
    const u16* kBase = qkv + (size_t)goff*QKV_DIM + F_DIM + h*144;
    int vOff[3];
    #pragma unroll
    for (int p = 0; p < 3; p++){
        int idx = p*256 + tid;
        if (idx > 575) idx = 575;
        int d = idx >> 2, c = idx & 3;
        vOff[p] = d*32 + ((c ^ (d & 3)) << 3);   // pre-swizzled src
    }
    const u16* vBase = Vpack + ((size_t)h*PT + (pst >> 5))*4608;
    const u16* bBase = biasP + ((size_t)boffg + (size_t)qtP*ntg)*8192 + h*1024 + li*32 + hi*16;

    int qnode = qbase + li; if (qnode >= gend) qnode = gend - 1;
    const u16* qrow = qkv + (size_t)qnode*QKV_DIM + h*144;
    bf16x8 qf[9];
    #pragma unroll
    for (int kk = 0; kk < 9; kk++) qf[kk] = *(const bf16x8*)(qrow + kk*16 + hi*8);

    int jlr[16];
    #pragma unroll
    for (int r = 0; r < 16; r++) jlr[r] = (r & 3) + ((r >> 2) << 3) + (hi << 2);

    float lrun = 0.f;
    f32x16 O[5];
    #pragma unroll
    for (int dt = 0; dt < 5; dt++)
        #pragma unroll
        for (int e = 0; e < 16; e++) O[dt][e] = 0.f;

    u32x4 bA0, bA1, bN0, bN1;
    bA0 = *(const u32x4*)bBase;
    bA1 = *(const u32x4*)(bBase + 8);
    {
        gload16(kBase + kOff[0], &sK[0][tid*8]);
        gload16(kBase + kOff[1], &sK[0][(256+tid)*8]);
        if (tid < 96) gload16(kBase + kOff[2], &sK[0][(512+tid)*8]);
        gload16(vBase + vOff[0], &sV[0][tid*8]);
        gload16(vBase + vOff[1], &sV[0][(256+tid)*8]);
        if (tid < 64) gload16(vBase + vOff[2], &sV[0][(512+tid)*8]);
    }
    __syncthreads();

    #pragma unroll 1
    for (int t = 0; t < ntg; t++){
        const int cur = t & 1;
        int tn = (t+1 < ntg) ? t+1 : ntg-1;
        bN0 = *(const u32x4*)(bBase + (size_t)tn*8192);
        bN1 = *(const u32x4*)(bBase + (size_t)tn*8192 + 8);
        __builtin_amdgcn_sched_barrier(0);
        if (t+1 < ntg){
            const u16* kb = kBase + (size_t)(t+1)*32*QKV_DIM;
            const u16* vb = vBase + (size_t)(t+1)*4608;
            gload16(kb + kOff[0], &sK[cur^1][tid*8]);
            gload16(kb + kOff[1], &sK[cur^1][(256+tid)*8]);
            if (tid < 96) gload16(kb + kOff[2], &sK[cur^1][(512+tid)*8]);
            gload16(vb + vOff[0], &sV[cur^1][tid*8]);
            gload16(vb + vOff[1], &sV[cur^1][(256+tid)*8]);
            if (tid < 64) gload16(vb + vOff[2], &sV[cur^1][(512+tid)*8]);
        }

        const u16* sKc = &sK[cur][0];
        f32x16 sacc;
        #pragma unroll
        for (int e = 0; e < 16; e++) sacc[e] = 0.f;
        __builtin_amdgcn_s_setprio(1);
        #pragma unroll
        for (int kk = 0; kk < 9; kk++){
            bf16x8 kf = *(const bf16x8*)(sKc + li*152 + kk*16 + hi*8);
            sacc = __builtin_amdgcn_mfma_f32_32x32x16_bf16(kf, qf[kk], sacc, 0, 0, 0);
        }
        __builtin_amdgcn_s_setprio(0);

        float bfv[16];
        #pragma unroll
        for (int q = 0; q < 4; q++){
            bfv[2*q]     = __builtin_bit_cast(float, bA0[q] << 16);
            bfv[2*q+1]   = __builtin_bit_cast(float, bA0[q] & 0xffff0000u);
            bfv[8+2*q]   = __builtin_bit_cast(float, bA1[q] << 16);
            bfv[8+2*q+1] = __builtin_bit_cast(float, bA1[q] & 0xffff0000u);
        }

        const int j0 = t*32;
        float p[16];
        float psum = 0.f;
        if (j0 + 32 <= ng){
            #pragma unroll
            for (int r = 0; r < 16; r++){
                float s_ = fminf(fmaf(sacc[r], KSC, bfv[r]), 86.f);
                p[r] = exp2f(s_); psum += p[r];
            }
        } else {
            #pragma unroll
            for (int r = 0; r < 16; r++){
                float s_ = fminf(fmaf(sacc[r], KSC, bfv[r]), 86.f);
                p[r] = (j0 + jlr[r] < ng) ? exp2f(s_) : 0.f;
                psum += p[r];
            }
        }
        psum += __shfl_xor(psum, 32);
        lrun += psum;

        u32 cpk[8], opk[8];
        #pragma unroll
        for (int q = 0; q < 8; q++) cpk[q] = cvtpk(p[2*q], p[2*q+1]);
        #pragma unroll
        for (int q = 0; q < 8; q++) opk[q] = (u32)__shfl_xor((int)cpk[q], 32);
        u32x4 a0, a1;
        if (hi == 0){
            a0[0]=cpk[0]; a0[1]=cpk[1]; a0[2]=opk[0]; a0[3]=opk[1];
            a1[0]=cpk[4]; a1[1]=cpk[5]; a1[2]=opk[4]; a1[3]=opk[5];
        } else {
            a0[0]=opk[2]; a0[1]=opk[3]; a0[2]=cpk[2]; a0[3]=cpk[3];
            a1[0]=opk[6]; a1[1]=opk[7]; a1[2]=cpk[6]; a1[3]=cpk[7];
        }
        bf16x8 paf0 = __builtin_bit_cast(bf16x8, a0);
        bf16x8 paf1 = __builtin_bit_cast(bf16x8, a1);

        const u16* sVc = &sV[cur][0];
        __builtin_amdgcn_s_setprio(1);
        #pragma unroll
        for (int dt = 0; dt < 5; dt++){
            int d = dt*32 + li;
            int dc = (d > 143) ? 143 : d;
            int swzlo = ((hi     ^ (dc & 3)) << 3);
            int swzhi = (((2+hi) ^ (dc & 3)) << 3);
            bf16x8 v0 = *(const bf16x8*)(sVc + dc*32 + swzlo);
            bf16x8 v1 = *(const bf16x8*)(sVc + dc*32 + swzhi);
            O[dt] = __builtin_amdgcn_mfma_f32_32x32x16_bf16(paf0, v0, O[dt], 0, 0, 0);
            O[dt] = __builtin_amdgcn_mfma_f32_32x32x16_bf16(paf1, v1, O[dt], 0, 0, 0);
        }
        __builtin_amdgcn_s_setprio(0);

        bA0 = bN0; bA1 = bN1;
        __syncthreads();
    }

    if (qt < ntg){
        float lr[16];
        #pragma unroll
        for (int r = 0; r < 16; r++) lr[r] = 1.0f / __shfl(lrun, jlr[r]);
        #pragma unroll
        for (int dt = 0; dt < 5; dt++){
            int d = dt*32 + li;
            if (d < 144){
                #pragma unroll
                for (int r = 0; r < 16; r++){
                    int qi = jlr[r];
                    if (qt*32 + qi < ng)
                        attn_out[(size_t)(qbase + qi)*F_DIM + h*144 + d] = f2bf(O[dt][r]*lr[r]);
                }
            }
        }
    }
}

// ---------------------------------------------------------------------------
// y = LayerNorm(x + out) * gamma + beta  (in-place over d_out)
// ---------------------------------------------------------------------------
__global__ __launch_bounds__(256) void ln_kernel(const float* __restrict__ x,
                                                 float* __restrict__ io,
                                                 const float* __restrict__ gamma,
                                                 const float* __restrict__ beta){
    const int node = blockIdx.x;
    const float* xr = x  + (size_t)node*F_DIM;
    float* yr       = io + (size_t)node*F_DIM;
    const int t = threadIdx.x;
    float h[5]; float s = 0.f, ss = 0.f;
    #pragma unroll
    for (int i = 0; i < 5; i++){
        int idx = t + i*256;
        float v = 0.f;
        if (idx < F_DIM) v = xr[idx] + yr[idx];
        h[i] = v; s += v; ss += v*v;
    }
    #pragma unroll
    for (int o = 32; o > 0; o >>= 1){ s += __shfl_down(s, o); ss += __shfl_down(ss, o); }
    __shared__ float rs[4], rss[4];
    __shared__ float smu, srstd;
    if ((t & 63) == 0){ rs[t>>6] = s; rss[t>>6] = ss; }
    __syncthreads();
    if (t == 0){
        float S  = rs[0]+rs[1]+rs[2]+rs[3];
        float SS = rss[0]+rss[1]+rss[2]+rss[3];
        float mu = S * (1.f/F_DIM);
        float var = SS * (1.f/F_DIM) - mu*mu;
        smu = mu; srstd = rsqrtf(var + 1e-5f);
    }
    __syncthreads();
    float mu = smu, rstd = srstd;
    #pragma unroll
    for (int i = 0; i < 5; i++){
        int idx = t + i*256;
        if (idx < F_DIM) yr[idx] = (h[i]-mu)*rstd*gamma[idx] + beta[idx];
    }
}

// ---------------------------------------------------------------------------
extern "C" void kernel_launch(void* const* d_in, const int* in_sizes, int n_in,
                              void* d_out, int out_size, void* d_ws, size_t ws_size,
                              hipStream_t stream){
    const float* x     = (const float*)d_in[0];
    const float* pos   = (const float*)d_in[1];
    const float* Wqkv  = (const float*)d_in[2];
    const float* Wout  = (const float*)d_in[3];
    const float* rfreq = (const float*)d_in[4];
    const float* Wrope = (const float*)d_in[5];
    const float* gamma = (const float*)d_in[6];
    const float* beta  = (const float*)d_in[7];
    const int*   batch = (const int*)d_in[8];

    const int N  = in_sizes[0] / F_DIM;     // 8192
    const int PN = N + 512;                 // padded columns
    const int PT = PN / 32;                 // padded tiles

    char* ws = (char*)d_ws;
    size_t off = 0;
    auto alloc = [&](size_t b){ size_t o = off; off += (b + 255) & ~(size_t)255; return o; };
    int* meta   = (int*)(ws + alloc((size_t)(64 + 2*MAX4 + 64)*sizeof(int)));
    u16* xb     = (u16*)(ws + alloc((size_t)N*F_DIM*2));        // reused as attn_out
    u16* wqkvT  = (u16*)(ws + alloc((size_t)QKV_DIM*F_DIM*2));
    u16* woutT  = (u16*)(ws + alloc((size_t)F_DIM*F_DIM*2));
    u16* qkv    = (u16*)(ws + alloc((size_t)N*QKV_DIM*2));
    u16* Vpack  = (u16*)(ws + alloc((size_t)8*PT*144*32*2));
    u16* biasb  = (u16*)(ws + off);         // rest of workspace: bias blocks
    (void)ws_size; (void)n_in; (void)out_size;

    const int n4    = N*F_DIM/4;
    const int nCast = (n4 + 255)/256;                       // 9216
    hipLaunchKernelGGL(prep_kernel, dim3(PREP_BLKS), dim3(256), 0, stream,
                       x, xb, nCast, n4, Wqkv, wqkvT, Wout, woutT,
                       pos, rfreq, Wrope, biasb, batch, meta, N);
    hipLaunchKernelGGL((gemm256<true>), dim3((N/256)*((QKV_DIM+255)/256)), dim3(512), 0, stream,
                       xb, wqkvT, (void*)qkv, N, QKV_DIM, F_DIM);
    hipLaunchKernelGGL(pack_v, dim3(N/32, 5, 8), dim3(256), 0, stream,
                       qkv, Vpack, batch, meta, PT);
    hipLaunchKernelGGL(attn_kernel, dim3(MAX4*8), dim3(256), 0, stream,
                       qkv, Vpack, biasb, xb, meta, PT);
    hipLaunchKernelGGL((gemm256<false>), dim3((N/256)*((F_DIM+255)/256)), dim3(512), 0, stream,
                       xb, woutT, d_out, N, F_DIM, F_DIM);
    hipLaunchKernelGGL(ln_kernel, dim3(N), dim3(256), 0, stream,
                       x, (float*)d_out, gamma, beta);
}

// Round 17
// 281.276 us; speedup vs baseline: 1.0364x; 1.0364x over previous
//
#include <hip/hip_runtime.h>

typedef unsigned short u16;
typedef unsigned int   u32;
typedef __attribute__((ext_vector_type(8)))  __bf16 bf16x8;
typedef __attribute__((ext_vector_type(4)))  float  f32x4;
typedef __attribute__((ext_vector_type(16))) float  f32x16;
typedef __attribute__((ext_vector_type(4)))  u32    u32x4;
typedef __attribute__((ext_vector_type(2)))  u32    u32x2;

#define F_DIM   1152
#define QKV_DIM 3456
#define HD_SCALE 0.083333333333333333f   // 1/sqrt(144)
#define LOG2E    1.4426950408889634f
#define KSC      (HD_SCALE*LOG2E)        // folded score scale (log2 domain)
#define MAX4    80                        // >= sum ceil(ntg/4) over graphs
#define BIAS_BLKS 2048

static __device__ __forceinline__ u16 f2bf(float f){
    u32 u = __builtin_bit_cast(u32, f);
    u32 r = u + 0x7fffu + ((u >> 16) & 1u);   // RNE
    return (u16)(r >> 16);
}
static __device__ __forceinline__ u32 cvtpk(float lo, float hi){
    u32 r;
    asm("v_cvt_pk_bf16_f32 %0, %1, %2" : "=v"(r) : "v"(lo), "v"(hi));
    return r;
}

typedef __attribute__((address_space(1))) void gvoid;
typedef __attribute__((address_space(3))) void lvoid;
static __device__ __forceinline__ void gload16(const u16* g, u16* l){
    __builtin_amdgcn_global_load_lds((gvoid*)g, (lvoid*)l, 16, 0, 0);
}

// ---------------------------------------------------------------------------
// prep_kernel (r15 version — empirically best): fused
// {bias table | cast x->bf16 | transpose W | meta}, bias blocks first.
// Bias stored *LOG2E, PERMUTED layout:
// biasP[bb*8192 + h*1024 + i*32 + c], j = (c&3) + ((c>>2)&3)*8 + (c>>4)*4.
// bias + cast use v_cvt_pk_bf16_f32 (1 op / 2 elems, u32 stores).
// ---------------------------------------------------------------------------
__global__ __launch_bounds__(256) void prep_kernel(
        const float* __restrict__ x, u16* __restrict__ xb, int nCast, int n4,
        const float* __restrict__ Wqkv, u16* __restrict__ wqkvT,
        const float* __restrict__ Wout, u16* __restrict__ woutT,
        const float* __restrict__ pos, const float* __restrict__ rfreq,
        const float* __restrict__ Wrope, u16* __restrict__ biasP,
        const int* __restrict__ batch, int* __restrict__ meta, int N){
    __shared__ float tile[32][33];
    __shared__ int goffs[17];
    __shared__ int bpre[17];
    const int b = blockIdx.x, t = threadIdx.x;
    const int T1 = (QKV_DIM/32)*(F_DIM/32);
    const int T2 = (F_DIM/32)*(F_DIM/32);

    if (b < BIAS_BLKS){
        if (t <= 16){
            int lo = 0, hi = N;
            while (lo < hi){ int mid = (lo+hi)>>1; if (batch[mid] < t) lo = mid+1; else hi = mid; }
            goffs[t] = lo;
        }
        __syncthreads();
        if (t == 0){
            int bc = 0;
            for (int g = 0; g < 16; g++){
                bpre[g] = bc;
                int ng = goffs[g+1] - goffs[g];
                int ntg = (ng + 31) >> 5;
                bc += ntg*ntg;
            }
            bpre[16] = bc;
        }
        __syncthreads();
        float absf[16], w[16][8];
        #pragma unroll
        for (int r = 0; r < 16; r++){
            absf[r] = fabsf(rfreq[r]);
            #pragma unroll
            for (int h = 0; h < 8; h++) w[r][h] = Wrope[r*8 + h] * LOG2E;
        }
        const int total = bpre[16];
        for (int bb = b; bb < total; bb += BIAS_BLKS){
            int g = 0;
            while (bpre[g+1] <= bb) g++;
            int rem  = bb - bpre[g];
            int goff = goffs[g];
            int ng   = goffs[g+1] - goff;
            int ntg  = (ng + 31) >> 5;
            int qt   = rem / ntg;
            int jt   = rem - qt*ntg;
            size_t base = (size_t)bb * 8192;
            #pragma unroll
            for (int pp = 0; pp < 2; pp++){
                const int p0 = pp*512 + 2*t;          // even; p0,p0+1 share i
                float bv0[8], bv1[8];
                #pragma unroll
                for (int h = 0; h < 8; h++){ bv0[h] = 0.f; bv1[h] = 0.f; }
                const int i = p0 >> 5;
                int qn = goff + qt*32 + i;  if (qn >= goff + ng) qn = goff + ng - 1;
                float qx = pos[qn*3+0], qy = pos[qn*3+1], qz = pos[qn*3+2];
                #pragma unroll
                for (int e = 0; e < 2; e++){
                    int c = (p0 + e) & 31;
                    int p4 = c & 15;
                    int j  = (p4 & 3) + ((p4 >> 2) << 3) + ((c >> 4) << 2);
                    int kn = goff + jt*32 + j;  if (kn >= goff + ng) kn = goff + ng - 1;
                    float dx = qx - pos[kn*3+0];
                    float dy = qy - pos[kn*3+1];
                    float dz = qz - pos[kn*3+2];
                    float d  = sqrtf(dx*dx + dy*dy + dz*dz);
                    float* bv = e ? bv1 : bv0;
                    #pragma unroll
                    for (int r = 0; r < 16; r++){
                        float cs = __cosf(d * absf[r]);
                        #pragma unroll
                        for (int h = 0; h < 8; h++) bv[h] = fmaf(cs, w[r][h], bv[h]);
                    }
                }
                #pragma unroll
                for (int h = 0; h < 8; h++)
                    *(u32*)&biasP[base + h*1024 + p0] = cvtpk(bv0[h], bv1[h]);
            }
        }
        return;
    }
    const int b2 = b - BIAS_BLKS;
    if (b2 < nCast){
        int i = b2*256 + t;
        if (i < n4){
            float4 v = ((const float4*)x)[i];
            u32x2 o; o[0] = cvtpk(v.x, v.y); o[1] = cvtpk(v.z, v.w);
            *(u32x2*)&xb[(size_t)i*4] = o;
        }
        return;
    }
    if (b2 < nCast + T1 + T2){
        const float* in; u16* out; int R, C, bi;
        if (b2 < nCast + T1){ in = Wqkv; out = wqkvT; R = F_DIM; C = QKV_DIM; bi = b2 - nCast; }
        else                { in = Wout; out = woutT; R = F_DIM; C = F_DIM;  bi = b2 - nCast - T1; }
        int gx = C/32;
        int c0 = (bi % gx)*32, r0 = (bi / gx)*32;
        int tx = t & 31, ty = t >> 5;
        #pragma unroll
        for (int yy = ty; yy < 32; yy += 8)
            tile[yy][tx] = in[(size_t)(r0+yy)*C + (c0+tx)];
        __syncthreads();
        #pragma unroll
        for (int yy = ty; yy < 32; yy += 8)
            out[(size_t)(c0+yy)*R + (r0+tx)] = f2bf(tile[tx][yy]);
        return;
    }
    // ---- meta (single block) ----
    if (t <= 16){
        int lo = 0, hi = N;
        while (lo < hi){ int mid = (lo+hi)>>1; if (batch[mid] < t) lo = mid+1; else hi = mid; }
        meta[1+t] = lo;
    }
    __syncthreads();
    if (t == 0){
        int ps = 0, bcnt = 0, cnt4 = 0;
        for (int g = 0; g < 16; g++){
            int ng = meta[2+g] - meta[1+g];
            meta[20+g] = ps;
            meta[40+g] = bcnt;
            int nt = (ng + 31) / 32;
            ps += nt * 32;
            bcnt += nt * nt;
            int nt4 = (nt + 3) / 4;
            for (int q4 = 0; q4 < nt4; q4++){
                meta[64 + cnt4] = g;
                meta[64 + MAX4 + cnt4] = q4;
                cnt4++;
            }
        }
        meta[36] = ps;
        meta[56] = bcnt;
        meta[0]  = cnt4;
    }
}

// ---------------------------------------------------------------------------
// gemm256 (round-12 v1): C[M,Ncols] = A[M,K]*Bt[Ncols,K]^T.
// 256x256 tile, 512 thr (8 waves 2Mx4N), BK=32, 4-deep LDS pipeline:
//   iter t: STAGE(t+2) -> s_waitcnt vmcnt(8)+s_barrier -> ds_read -> 32 MFMA.
// vmcnt never drains to 0 (T4); one barrier/K-step. T2 chunk-XOR swizzle via
// pre-swizzled source; T1 XCD swizzle; T5 setprio.
// ---------------------------------------------------------------------------
template<bool OUT_BF16>
__global__ __launch_bounds__(512, 2) void gemm256(const u16* __restrict__ A,
                                                  const u16* __restrict__ Bt,
                                                  void* __restrict__ Cp,
                                                  int M, int Ncols, int K){
    __shared__ u16 sA[4][8192];
    __shared__ u16 sB[4][8192];
    const int nwg = gridDim.x;
    int orig = blockIdx.x;
    int qq = nwg >> 3, rr = nwg & 7;
    int xcd = orig & 7, pos = orig >> 3;
    int nid = (xcd < rr ? xcd*(qq+1) : rr*(qq+1) + (xcd-rr)*qq) + pos;
    const int gx = M >> 8;
    const int bm = (nid % gx) << 8, bn = (nid / gx) << 8;

    const int tid = threadIdx.x;
    const int w = tid >> 6, lane = tid & 63;
    const int wr = w >> 2, wc = w & 3;
    const int fr = lane & 15, fq = lane >> 4;
    const int swz8 = (fq ^ ((fr >> 1) & 3)) * 8;

    const u16* aS[2]; const u16* bS[2]; int dOf[2];
    #pragma unroll
    for (int p = 0; p < 2; p++){
        int idx = p*512 + tid;
        int row = idx >> 2, c = idx & 3;
        int sc = c ^ ((row >> 1) & 3);
        int brow = bn + row; if (brow > Ncols-1) brow = Ncols-1;
        aS[p] = A  + (size_t)(bm + row)*K + sc*8;
        bS[p] = Bt + (size_t)brow*K + sc*8;
        dOf[p] = idx*8;
    }

    f32x4 acc[8][4];
    #pragma unroll
    for (int m = 0; m < 8; m++)
        #pragma unroll
        for (int n = 0; n < 4; n++)
            #pragma unroll
            for (int e = 0; e < 4; e++) acc[m][n][e] = 0.f;

    const int nk = K >> 5;
    #pragma unroll
    for (int p = 0; p < 2; p++){ gload16(aS[p], &sA[0][dOf[p]]); gload16(bS[p], &sB[0][dOf[p]]); }
    #pragma unroll
    for (int p = 0; p < 2; p++){ gload16(aS[p]+32, &sA[1][dOf[p]]); gload16(bS[p]+32, &sB[1][dOf[p]]); }

    #pragma unroll 1
    for (int t = 0; t < nk; t++){
        int tp = (t+2 < nk) ? t+2 : nk-1;
        int bufS = (t+2) & 3;
        #pragma unroll
        for (int p = 0; p < 2; p++){
            gload16(aS[p] + tp*32, &sA[bufS][dOf[p]]);
            gload16(bS[p] + tp*32, &sB[bufS][dOf[p]]);
        }
        asm volatile("s_waitcnt vmcnt(8)\n\ts_barrier" ::: "memory");

        const u16* sAc = &sA[t & 3][0];
        const u16* sBc = &sB[t & 3][0];
        bf16x8 af[8], bfr[4];
        #pragma unroll
        for (int m = 0; m < 8; m++)
            af[m] = *(const bf16x8*)(sAc + (wr*128 + m*16 + fr)*32 + swz8);
        #pragma unroll
        for (int n = 0; n < 4; n++)
            bfr[n] = *(const bf16x8*)(sBc + (wc*64 + n*16 + fr)*32 + swz8);
        __builtin_amdgcn_s_setprio(1);
        #pragma unroll
        for (int m = 0; m < 8; m++)
            #pragma unroll
            for (int n = 0; n < 4; n++)
                acc[m][n] = __builtin_amdgcn_mfma_f32_16x16x32_bf16(af[m], bfr[n], acc[m][n], 0, 0, 0);
        __builtin_amdgcn_s_setprio(0);
    }

    #pragma unroll
    for (int m = 0; m < 8; m++)
        #pragma unroll
        for (int n = 0; n < 4; n++)
            #pragma unroll
            for (int r = 0; r < 4; r++){
                int row = bm + wr*128 + m*16 + fq*4 + r;
                int col = bn + wc*64 + n*16 + fr;
                if (col < Ncols){
                    float v = acc[m][n][r];
                    if (OUT_BF16) ((u16*)Cp)[(size_t)row*Ncols + col] = f2bf(v);
                    else          ((float*)Cp)[(size_t)row*Ncols + col] = v;
                }
            }
}

// ---------------------------------------------------------------------------
// Vpack[h][ptile][d=144][key&31] = v[node][h*144+d] ; dense 9KB per KV tile.
// ---------------------------------------------------------------------------
__global__ __launch_bounds__(256) void pack_v(const u16* __restrict__ qkv,
                                              u16* __restrict__ Vpack,
                                              const int* __restrict__ batch,
                                              const int* __restrict__ meta,
                                              int PT){
    __shared__ u16 tile[32][33];
    int nt0 = blockIdx.x*32, dt0 = blockIdx.y*32, h = blockIdx.z;
    int tx = threadIdx.x & 31, ty = threadIdx.x >> 5;
    #pragma unroll
    for (int yy = ty; yy < 32; yy += 8){
        int node = nt0+yy, d = dt0+tx;
        tile[yy][tx] = (d < 144) ? qkv[(size_t)node*QKV_DIM + 2*F_DIM + h*144 + d] : (u16)0;
    }
    __syncthreads();
    int node = nt0 + tx;
    int g = batch[node];
    int col = meta[20+g] + (node - meta[1+g]);
    int pt = col >> 5, cl = col & 31;
    #pragma unroll
    for (int yy = ty; yy < 32; yy += 8){
        int d = dt0+yy;
        if (d < 144) Vpack[(((size_t)h*PT + pt)*144 + d)*32 + cl] = tile[tx][yy];
    }
}

// ---------------------------------------------------------------------------
// Flash attention: KVBLK=32, block = 4 waves = 4 q-tiles of one (graph,head).
// 38KB LDS -> 3 blocks/CU. No-max softmax, cvt_pk P-pack, setprio,
// reg-double-buffered bias (coalesced b128 from permuted table).
// ---------------------------------------------------------------------------
__global__ __launch_bounds__(256) void attn_kernel(
        const u16* __restrict__ qkv, const u16* __restrict__ Vpack,
        const u16* __restrict__ biasP, u16* __restrict__ attn_out,
        const int* __restrict__ meta, int PT){
    __shared__ u16 sK[2][4864];   // 32 rows x 304B (19 chunks, pad dup)
    __shared__ u16 sV[2][4608];   // [144][32] chunk-XOR swizzled
    const int h = blockIdx.x & 7, t4 = blockIdx.x >> 3;
    if (t4 >= meta[0]) return;
    const int g    = meta[64 + t4];
    const int q4   = meta[64 + MAX4 + t4];
    const int goff = meta[1+g], gend = meta[2+g];
    const int ng   = gend - goff;
    const int ntg  = (ng + 31) >> 5;
    const int pst  = meta[20+g];
    const int boffg= meta[40+g];

    const int tid = threadIdx.x;
    const int w = tid >> 6, lane = tid & 63;
    const int li = lane & 31, hi = lane >> 5;
    const int qt = q4*4 + w;
    const int qbase = goff + qt*32;
    const int qtP = (qt < ntg) ? qt : (ntg - 1);

    int kOff[3];
    #pragma unroll
    for (int p = 0; p < 3; p++){
        int idx = p*256 + tid;
        if (idx > 607) idx = 607;
        int row = idx/19, c = idx - row*19;
        if (c == 18) c = 0;
        kOff[p] = row*QKV_DIM + c*8;
    }
    const u16* kBase = qkv + (size_t)goff*QKV_DIM + F_DIM + h*144;
    int vOff[3];
    #pragma unroll
    for (int p = 0; p < 3; p++){
        int idx = p*256 + tid;
        if (idx > 575) idx = 575;
        int d = idx >> 2, c = idx & 3;
        vOff[p] = d*32 + ((c ^ (d & 3)) << 3);   // pre-swizzled src
    }
    const u16* vBase = Vpack + ((size_t)h*PT + (pst >> 5))*4608;
    const u16* bBase = biasP + ((size_t)boffg + (size_t)qtP*ntg)*8192 + h*1024 + li*32 + hi*16;

    int qnode = qbase + li; if (qnode >= gend) qnode = gend - 1;
    const u16* qrow = qkv + (size_t)qnode*QKV_DIM + h*144;
    bf16x8 qf[9];
    #pragma unroll
    for (int kk = 0; kk < 9; kk++) qf[kk] = *(const bf16x8*)(qrow + kk*16 + hi*8);

    int jlr[16];
    #pragma unroll
    for (int r = 0; r < 16; r++) jlr[r] = (r & 3) + ((r >> 2) << 3) + (hi << 2);

    float lrun = 0.f;
    f32x16 O[5];
    #pragma unroll
    for (int dt = 0; dt < 5; dt++)
        #pragma unroll
        for (int e = 0; e < 16; e++) O[dt][e] = 0.f;

    u32x4 bA0, bA1, bN0, bN1;
    bA0 = *(const u32x4*)bBase;
    bA1 = *(const u32x4*)(bBase + 8);
    {
        gload16(kBase + kOff[0], &sK[0][tid*8]);
        gload16(kBase + kOff[1], &sK[0][(256+tid)*8]);
        if (tid < 96) gload16(kBase + kOff[2], &sK[0][(512+tid)*8]);
        gload16(vBase + vOff[0], &sV[0][tid*8]);
        gload16(vBase + vOff[1], &sV[0][(256+tid)*8]);
        if (tid < 64) gload16(vBase + vOff[2], &sV[0][(512+tid)*8]);
    }
    __syncthreads();

    #pragma unroll 1
    for (int t = 0; t < ntg; t++){
        const int cur = t & 1;
        int tn = (t+1 < ntg) ? t+1 : ntg-1;
        bN0 = *(const u32x4*)(bBase + (size_t)tn*8192);
        bN1 = *(const u32x4*)(bBase + (size_t)tn*8192 + 8);
        __builtin_amdgcn_sched_barrier(0);
        if (t+1 < ntg){
            const u16* kb = kBase + (size_t)(t+1)*32*QKV_DIM;
            const u16* vb = vBase + (size_t)(t+1)*4608;
            gload16(kb + kOff[0], &sK[cur^1][tid*8]);
            gload16(kb + kOff[1], &sK[cur^1][(256+tid)*8]);
            if (tid < 96) gload16(kb + kOff[2], &sK[cur^1][(512+tid)*8]);
            gload16(vb + vOff[0], &sV[cur^1][tid*8]);
            gload16(vb + vOff[1], &sV[cur^1][(256+tid)*8]);
            if (tid < 64) gload16(vb + vOff[2], &sV[cur^1][(512+tid)*8]);
        }

        const u16* sKc = &sK[cur][0];
        f32x16 sacc;
        #pragma unroll
        for (int e = 0; e < 16; e++) sacc[e] = 0.f;
        __builtin_amdgcn_s_setprio(1);
        #pragma unroll
        for (int kk = 0; kk < 9; kk++){
            bf16x8 kf = *(const bf16x8*)(sKc + li*152 + kk*16 + hi*8);
            sacc = __builtin_amdgcn_mfma_f32_32x32x16_bf16(kf, qf[kk], sacc, 0, 0, 0);
        }
        __builtin_amdgcn_s_setprio(0);

        float bfv[16];
        #pragma unroll
        for (int q = 0; q < 4; q++){
            bfv[2*q]     = __builtin_bit_cast(float, bA0[q] << 16);
            bfv[2*q+1]   = __builtin_bit_cast(float, bA0[q] & 0xffff0000u);
            bfv[8+2*q]   = __builtin_bit_cast(float, bA1[q] << 16);
            bfv[8+2*q+1] = __builtin_bit_cast(float, bA1[q] & 0xffff0000u);
        }

        const int j0 = t*32;
        float p[16];
        float psum = 0.f;
        if (j0 + 32 <= ng){
            #pragma unroll
            for (int r = 0; r < 16; r++){
                float s_ = fminf(fmaf(sacc[r], KSC, bfv[r]), 86.f);
                p[r] = exp2f(s_); psum += p[r];
            }
        } else {
            #pragma unroll
            for (int r = 0; r < 16; r++){
                float s_ = fminf(fmaf(sacc[r], KSC, bfv[r]), 86.f);
                p[r] = (j0 + jlr[r] < ng) ? exp2f(s_) : 0.f;
                psum += p[r];
            }
        }
        psum += __shfl_xor(psum, 32);
        lrun += psum;

        u32 cpk[8], opk[8];
        #pragma unroll
        for (int q = 0; q < 8; q++) cpk[q] = cvtpk(p[2*q], p[2*q+1]);
        #pragma unroll
        for (int q = 0; q < 8; q++) opk[q] = (u32)__shfl_xor((int)cpk[q], 32);
        u32x4 a0, a1;
        if (hi == 0){
            a0[0]=cpk[0]; a0[1]=cpk[1]; a0[2]=opk[0]; a0[3]=opk[1];
            a1[0]=cpk[4]; a1[1]=cpk[5]; a1[2]=opk[4]; a1[3]=opk[5];
        } else {
            a0[0]=opk[2]; a0[1]=opk[3]; a0[2]=cpk[2]; a0[3]=cpk[3];
            a1[0]=opk[6]; a1[1]=opk[7]; a1[2]=cpk[6]; a1[3]=cpk[7];
        }
        bf16x8 paf0 = __builtin_bit_cast(bf16x8, a0);
        bf16x8 paf1 = __builtin_bit_cast(bf16x8, a1);

        const u16* sVc = &sV[cur][0];
        __builtin_amdgcn_s_setprio(1);
        #pragma unroll
        for (int dt = 0; dt < 5; dt++){
            int d = dt*32 + li;
            int dc = (d > 143) ? 143 : d;
            int swzlo = ((hi     ^ (dc & 3)) << 3);
            int swzhi = (((2+hi) ^ (dc & 3)) << 3);
            bf16x8 v0 = *(const bf16x8*)(sVc + dc*32 + swzlo);
            bf16x8 v1 = *(const bf16x8*)(sVc + dc*32 + swzhi);
            O[dt] = __builtin_amdgcn_mfma_f32_32x32x16_bf16(paf0, v0, O[dt], 0, 0, 0);
            O[dt] = __builtin_amdgcn_mfma_f32_32x32x16_bf16(paf1, v1, O[dt], 0, 0, 0);
        }
        __builtin_amdgcn_s_setprio(0);

        bA0 = bN0; bA1 = bN1;
        __syncthreads();
    }

    if (qt < ntg){
        float lr[16];
        #pragma unroll
        for (int r = 0; r < 16; r++) lr[r] = 1.0f / __shfl(lrun, jlr[r]);
        #pragma unroll
        for (int dt = 0; dt < 5; dt++){
            int d = dt*32 + li;
            if (d < 144){
                #pragma unroll
                for (int r = 0; r < 16; r++){
                    int qi = jlr[r];
                    if (qt*32 + qi < ng)
                        attn_out[(size_t)(qbase + qi)*F_DIM + h*144 + d] = f2bf(O[dt][r]*lr[r]);
                }
            }
        }
    }
}

// ---------------------------------------------------------------------------
// y = LayerNorm(x + out) * gamma + beta  (in-place over d_out)
// v17: float4 vectorized loads/stores (288 f4/row: all threads 1, t<32 a 2nd)
// ---------------------------------------------------------------------------
__global__ __launch_bounds__(256) void ln_kernel(const float* __restrict__ x,
                                                 float* __restrict__ io,
                                                 const float* __restrict__ gamma,
                                                 const float* __restrict__ beta){
    const int node = blockIdx.x;
    const float4* xr = (const float4*)(x  + (size_t)node*F_DIM);
    float4* yr       = (float4*)(io + (size_t)node*F_DIM);
    const int t = threadIdx.x;
    float4 h0, h1;
    float s = 0.f, ss = 0.f;
    {
        float4 a = xr[t], v = yr[t];
        h0.x = a.x+v.x; h0.y = a.y+v.y; h0.z = a.z+v.z; h0.w = a.w+v.w;
        s  += h0.x + h0.y + h0.z + h0.w;
        ss += h0.x*h0.x + h0.y*h0.y + h0.z*h0.z + h0.w*h0.w;
    }
    if (t < 32){
        float4 a = xr[256+t], v = yr[256+t];
        h1.x = a.x+v.x; h1.y = a.y+v.y; h1.z = a.z+v.z; h1.w = a.w+v.w;
        s  += h1.x + h1.y + h1.z + h1.w;
        ss += h1.x*h1.x + h1.y*h1.y + h1.z*h1.z + h1.w*h1.w;
    }
    #pragma unroll
    for (int o = 32; o > 0; o >>= 1){ s += __shfl_down(s, o); ss += __shfl_down(ss, o); }
    __shared__ float rs[4], rss[4];
    __shared__ float smu, srstd;
    if ((t & 63) == 0){ rs[t>>6] = s; rss[t>>6] = ss; }
    __syncthreads();
    if (t == 0){
        float S  = rs[0]+rs[1]+rs[2]+rs[3];
        float SS = rss[0]+rss[1]+rss[2]+rss[3];
        float mu = S * (1.f/F_DIM);
        float var = SS * (1.f/F_DIM) - mu*mu;
        smu = mu; srstd = rsqrtf(var + 1e-5f);
    }
    __syncthreads();
    float mu = smu, rstd = srstd;
    {
        float4 gv = ((const float4*)gamma)[t];
        float4 bv = ((const float4*)beta)[t];
        float4 o;
        o.x = (h0.x-mu)*rstd*gv.x + bv.x;
        o.y = (h0.y-mu)*rstd*gv.y + bv.y;
        o.z = (h0.z-mu)*rstd*gv.z + bv.z;
        o.w = (h0.w-mu)*rstd*gv.w + bv.w;
        yr[t] = o;
    }
    if (t < 32){
        float4 gv = ((const float4*)gamma)[256+t];
        float4 bv = ((const float4*)beta)[256+t];
        float4 o;
        o.x = (h1.x-mu)*rstd*gv.x + bv.x;
        o.y = (h1.y-mu)*rstd*gv.y + bv.y;
        o.z = (h1.z-mu)*rstd*gv.z + bv.z;
        o.w = (h1.w-mu)*rstd*gv.w + bv.w;
        yr[256+t] = o;
    }
}

// ---------------------------------------------------------------------------
extern "C" void kernel_launch(void* const* d_in, const int* in_sizes, int n_in,
                              void* d_out, int out_size, void* d_ws, size_t ws_size,
                              hipStream_t stream){
    const float* x     = (const float*)d_in[0];
    const float* pos   = (const float*)d_in[1];
    const float* Wqkv  = (const float*)d_in[2];
    const float* Wout  = (const float*)d_in[3];
    const float* rfreq = (const float*)d_in[4];
    const float* Wrope = (const float*)d_in[5];
    const float* gamma = (const float*)d_in[6];
    const float* beta  = (const float*)d_in[7];
    const int*   batch = (const int*)d_in[8];

    const int N  = in_sizes[0] / F_DIM;     // 8192
    const int PN = N + 512;                 // padded columns
    const int PT = PN / 32;                 // padded tiles

    char* ws = (char*)d_ws;
    size_t off = 0;
    auto alloc = [&](size_t b){ size_t o = off; off += (b + 255) & ~(size_t)255; return o; };
    int* meta   = (int*)(ws + alloc((size_t)(64 + 2*MAX4 + 64)*sizeof(int)));
    u16* xb     = (u16*)(ws + alloc((size_t)N*F_DIM*2));        // reused as attn_out
    u16* wqkvT  = (u16*)(ws + alloc((size_t)QKV_DIM*F_DIM*2));
    u16* woutT  = (u16*)(ws + alloc((size_t)F_DIM*F_DIM*2));
    u16* qkv    = (u16*)(ws + alloc((size_t)N*QKV_DIM*2));
    u16* Vpack  = (u16*)(ws + alloc((size_t)8*PT*144*32*2));
    u16* biasb  = (u16*)(ws + off);         // rest of workspace: bias blocks
    (void)ws_size; (void)n_in; (void)out_size;

    const int n4    = N*F_DIM/4;
    const int nCast = (n4 + 255)/256;                       // 9216
    const int nT    = (QKV_DIM/32)*(F_DIM/32) + (F_DIM/32)*(F_DIM/32);  // 5184
    hipLaunchKernelGGL(prep_kernel, dim3(BIAS_BLKS + nCast + nT + 1), dim3(256), 0, stream,
                       x, xb, nCast, n4, Wqkv, wqkvT, Wout, woutT,
                       pos, rfreq, Wrope, biasb, batch, meta, N);
    hipLaunchKernelGGL((gemm256<true>), dim3((N/256)*((QKV_DIM+255)/256)), dim3(512), 0, stream,
                       xb, wqkvT, (void*)qkv, N, QKV_DIM, F_DIM);
    hipLaunchKernelGGL(pack_v, dim3(N/32, 5, 8), dim3(256), 0, stream,
                       qkv, Vpack, batch, meta, PT);
    hipLaunchKernelGGL(attn_kernel, dim3(MAX4*8), dim3(256), 0, stream,
                       qkv, Vpack, biasb, xb, meta, PT);
    hipLaunchKernelGGL((gemm256<false>), dim3((N/256)*((F_DIM+255)/256)), dim3(512), 0, stream,
                       xb, woutT, d_out, N, F_DIM, F_DIM);
    hipLaunchKernelGGL(ln_kernel, dim3(N), dim3(256), 0, stream,
                       x, (float*)d_out, gamma, beta);
}

// Round 18
// 276.465 us; speedup vs baseline: 1.0545x; 1.0174x over previous
//
#include <hip/hip_runtime.h>

typedef unsigned short u16;
typedef unsigned int   u32;
typedef __attribute__((ext_vector_type(8)))  __bf16 bf16x8;
typedef __attribute__((ext_vector_type(4)))  float  f32x4;
typedef __attribute__((ext_vector_type(16))) float  f32x16;
typedef __attribute__((ext_vector_type(4)))  u32    u32x4;
typedef __attribute__((ext_vector_type(2)))  u32    u32x2;

#define F_DIM   1152
#define QKV_DIM 3456
#define HD_SCALE 0.083333333333333333f   // 1/sqrt(144)
#define LOG2E    1.4426950408889634f
#define KSC      (HD_SCALE*LOG2E)        // folded score scale (log2 domain)
#define MAX4    80                        // >= sum ceil(ntg/4) over graphs
#define BIAS_BLKS 2048

static __device__ __forceinline__ u16 f2bf(float f){
    u32 u = __builtin_bit_cast(u32, f);
    u32 r = u + 0x7fffu + ((u >> 16) & 1u);   // RNE
    return (u16)(r >> 16);
}
static __device__ __forceinline__ u32 cvtpk(float lo, float hi){
    u32 r;
    asm("v_cvt_pk_bf16_f32 %0, %1, %2" : "=v"(r) : "v"(lo), "v"(hi));
    return r;
}

typedef __attribute__((address_space(1))) void gvoid;
typedef __attribute__((address_space(3))) void lvoid;
static __device__ __forceinline__ void gload16(const u16* g, u16* l){
    __builtin_amdgcn_global_load_lds((gvoid*)g, (lvoid*)l, 16, 0, 0);
}

// ---------------------------------------------------------------------------
// prep_kernel v18: fused {bias table | cast x->bf16 | transpose W | meta},
// bias blocks first (empirically best ordering), MEMORY BLOCKS FATTENED:
// cast blocks do 8 independent float4 chunks (latency pipelines), transpose
// blocks do 4 tiles. Bias stored *LOG2E, PERMUTED layout:
// biasP[bb*8192 + h*1024 + i*32 + c], j = (c&3) + ((c>>2)&3)*8 + (c>>4)*4.
// grid = 2048 bias + 1152 cast + 1296 transpose + 1 meta = 4497.
// ---------------------------------------------------------------------------
__global__ __launch_bounds__(256) void prep_kernel(
        const float* __restrict__ x, u16* __restrict__ xb, int n4,
        const float* __restrict__ Wqkv, u16* __restrict__ wqkvT,
        const float* __restrict__ Wout, u16* __restrict__ woutT,
        const float* __restrict__ pos, const float* __restrict__ rfreq,
        const float* __restrict__ Wrope, u16* __restrict__ biasP,
        const int* __restrict__ batch, int* __restrict__ meta, int N){
    __shared__ float tile[32][33];
    __shared__ int goffs[17];
    __shared__ int bpre[17];
    const int b = blockIdx.x, t = threadIdx.x;
    const int T1 = (QKV_DIM/32)*(F_DIM/32);   // 3888

    if (b < BIAS_BLKS){
        if (t <= 16){
            int lo = 0, hi = N;
            while (lo < hi){ int mid = (lo+hi)>>1; if (batch[mid] < t) lo = mid+1; else hi = mid; }
            goffs[t] = lo;
        }
        __syncthreads();
        if (t == 0){
            int bc = 0;
            for (int g = 0; g < 16; g++){
                bpre[g] = bc;
                int ng = goffs[g+1] - goffs[g];
                int ntg = (ng + 31) >> 5;
                bc += ntg*ntg;
            }
            bpre[16] = bc;
        }
        __syncthreads();
        float absf[16], w[16][8];
        #pragma unroll
        for (int r = 0; r < 16; r++){
            absf[r] = fabsf(rfreq[r]);
            #pragma unroll
            for (int h = 0; h < 8; h++) w[r][h] = Wrope[r*8 + h] * LOG2E;
        }
        const int total = bpre[16];
        for (int bb = b; bb < total; bb += BIAS_BLKS){
            int g = 0;
            while (bpre[g+1] <= bb) g++;
            int rem  = bb - bpre[g];
            int goff = goffs[g];
            int ng   = goffs[g+1] - goff;
            int ntg  = (ng + 31) >> 5;
            int qt   = rem / ntg;
            int jt   = rem - qt*ntg;
            size_t base = (size_t)bb * 8192;
            #pragma unroll
            for (int pp = 0; pp < 2; pp++){
                const int p0 = pp*512 + 2*t;          // even; p0,p0+1 share i
                float bv0[8], bv1[8];
                #pragma unroll
                for (int h = 0; h < 8; h++){ bv0[h] = 0.f; bv1[h] = 0.f; }
                const int i = p0 >> 5;
                int qn = goff + qt*32 + i;  if (qn >= goff + ng) qn = goff + ng - 1;
                float qx = pos[qn*3+0], qy = pos[qn*3+1], qz = pos[qn*3+2];
                #pragma unroll
                for (int e = 0; e < 2; e++){
                    int c = (p0 + e) & 31;
                    int p4 = c & 15;
                    int j  = (p4 & 3) + ((p4 >> 2) << 3) + ((c >> 4) << 2);
                    int kn = goff + jt*32 + j;  if (kn >= goff + ng) kn = goff + ng - 1;
                    float dx = qx - pos[kn*3+0];
                    float dy = qy - pos[kn*3+1];
                    float dz = qz - pos[kn*3+2];
                    float d  = sqrtf(dx*dx + dy*dy + dz*dz);
                    float* bv = e ? bv1 : bv0;
                    #pragma unroll
                    for (int r = 0; r < 16; r++){
                        float cs = __cosf(d * absf[r]);
                        #pragma unroll
                        for (int h = 0; h < 8; h++) bv[h] = fmaf(cs, w[r][h], bv[h]);
                    }
                }
                #pragma unroll
                for (int h = 0; h < 8; h++)
                    *(u32*)&biasP[base + h*1024 + p0] = cvtpk(bv0[h], bv1[h]);
            }
        }
        return;
    }
    const int b2 = b - BIAS_BLKS;
    if (b2 < 1152){                           // fat cast: 2048 float4 / block
        const float4* xin = (const float4*)x;
        const size_t base = (size_t)b2*2048 + t;
        #pragma unroll
        for (int k2 = 0; k2 < 8; k2++){
            size_t i = base + k2*256;         // 8 independent load/store pairs
            float4 v = xin[i];
            u32x2 o; o[0] = cvtpk(v.x, v.y); o[1] = cvtpk(v.z, v.w);
            *(u32x2*)&xb[i*4] = o;
        }
        return;
    }
    const int b3 = b2 - 1152;
    if (b3 < 1296){                           // fat transpose: 4 tiles / block
        #pragma unroll 1
        for (int k2 = 0; k2 < 4; k2++){
            int u = b3*4 + k2;                // 0..5183
            const float* in; u16* out; int R, C, bi;
            if (u < T1){ in = Wqkv; out = wqkvT; R = F_DIM; C = QKV_DIM; bi = u; }
            else       { in = Wout; out = woutT; R = F_DIM; C = F_DIM;  bi = u - T1; }
            int gx = C/32;
            int c0 = (bi % gx)*32, r0 = (bi / gx)*32;
            int tx = t & 31, ty = t >> 5;
            __syncthreads();                  // tile[] reuse guard
            #pragma unroll
            for (int yy = ty; yy < 32; yy += 8)
                tile[yy][tx] = in[(size_t)(r0+yy)*C + (c0+tx)];
            __syncthreads();
            #pragma unroll
            for (int yy = ty; yy < 32; yy += 8)
                out[(size_t)(c0+yy)*R + (r0+tx)] = f2bf(tile[tx][yy]);
        }
        return;
    }
    // ---- meta (single block) ----
    if (t <= 16){
        int lo = 0, hi = N;
        while (lo < hi){ int mid = (lo+hi)>>1; if (batch[mid] < t) lo = mid+1; else hi = mid; }
        meta[1+t] = lo;
    }
    __syncthreads();
    if (t == 0){
        int ps = 0, bcnt = 0, cnt4 = 0;
        for (int g = 0; g < 16; g++){
            int ng = meta[2+g] - meta[1+g];
            meta[20+g] = ps;
            meta[40+g] = bcnt;
            int nt = (ng + 31) / 32;
            ps += nt * 32;
            bcnt += nt * nt;
            int nt4 = (nt + 3) / 4;
            for (int q4 = 0; q4 < nt4; q4++){
                meta[64 + cnt4] = g;
                meta[64 + MAX4 + cnt4] = q4;
                cnt4++;
            }
        }
        meta[36] = ps;
        meta[56] = bcnt;
        meta[0]  = cnt4;
    }
}

// ---------------------------------------------------------------------------
// gemm256 (round-12 v1): C[M,Ncols] = A[M,K]*Bt[Ncols,K]^T.
// 256x256 tile, 512 thr (8 waves 2Mx4N), BK=32, 4-deep LDS pipeline:
//   iter t: STAGE(t+2) -> s_waitcnt vmcnt(8)+s_barrier -> ds_read -> 32 MFMA.
// vmcnt never drains to 0 (T4); one barrier/K-step. T2 chunk-XOR swizzle via
// pre-swizzled source; T1 XCD swizzle; T5 setprio.
// ---------------------------------------------------------------------------
template<bool OUT_BF16>
__global__ __launch_bounds__(512, 2) void gemm256(const u16* __restrict__ A,
                                                  const u16* __restrict__ Bt,
                                                  void* __restrict__ Cp,
                                                  int M, int Ncols, int K){
    __shared__ u16 sA[4][8192];
    __shared__ u16 sB[4][8192];
    const int nwg = gridDim.x;
    int orig = blockIdx.x;
    int qq = nwg >> 3, rr = nwg & 7;
    int xcd = orig & 7, pos = orig >> 3;
    int nid = (xcd < rr ? xcd*(qq+1) : rr*(qq+1) + (xcd-rr)*qq) + pos;
    const int gx = M >> 8;
    const int bm = (nid % gx) << 8, bn = (nid / gx) << 8;

    const int tid = threadIdx.x;
    const int w = tid >> 6, lane = tid & 63;
    const int wr = w >> 2, wc = w & 3;
    const int fr = lane & 15, fq = lane >> 4;
    const int swz8 = (fq ^ ((fr >> 1) & 3)) * 8;

    const u16* aS[2]; const u16* bS[2]; int dOf[2];
    #pragma unroll
    for (int p = 0; p < 2; p++){
        int idx = p*512 + tid;
        int row = idx >> 2, c = idx & 3;
        int sc = c ^ ((row >> 1) & 3);
        int brow = bn + row; if (brow > Ncols-1) brow = Ncols-1;
        aS[p] = A  + (size_t)(bm + row)*K + sc*8;
        bS[p] = Bt + (size_t)brow*K + sc*8;
        dOf[p] = idx*8;
    }

    f32x4 acc[8][4];
    #pragma unroll
    for (int m = 0; m < 8; m++)
        #pragma unroll
        for (int n = 0; n < 4; n++)
            #pragma unroll
            for (int e = 0; e < 4; e++) acc[m][n][e] = 0.f;

    const int nk = K >> 5;
    #pragma unroll
    for (int p = 0; p < 2; p++){ gload16(aS[p], &sA[0][dOf[p]]); gload16(bS[p], &sB[0][dOf[p]]); }
    #pragma unroll
    for (int p = 0; p < 2; p++){ gload16(aS[p]+32, &sA[1][dOf[p]]); gload16(bS[p]+32, &sB[1][dOf[p]]); }

    #pragma unroll 1
    for (int t = 0; t < nk; t++){
        int tp = (t+2 < nk) ? t+2 : nk-1;
        int bufS = (t+2) & 3;
        #pragma unroll
        for (int p = 0; p < 2; p++){
            gload16(aS[p] + tp*32, &sA[bufS][dOf[p]]);
            gload16(bS[p] + tp*32, &sB[bufS][dOf[p]]);
        }
        asm volatile("s_waitcnt vmcnt(8)\n\ts_barrier" ::: "memory");

        const u16* sAc = &sA[t & 3][0];
        const u16* sBc = &sB[t & 3][0];
        bf16x8 af[8], bfr[4];
        #pragma unroll
        for (int m = 0; m < 8; m++)
            af[m] = *(const bf16x8*)(sAc + (wr*128 + m*16 + fr)*32 + swz8);
        #pragma unroll
        for (int n = 0; n < 4; n++)
            bfr[n] = *(const bf16x8*)(sBc + (wc*64 + n*16 + fr)*32 + swz8);
        __builtin_amdgcn_s_setprio(1);
        #pragma unroll
        for (int m = 0; m < 8; m++)
            #pragma unroll
            for (int n = 0; n < 4; n++)
                acc[m][n] = __builtin_amdgcn_mfma_f32_16x16x32_bf16(af[m], bfr[n], acc[m][n], 0, 0, 0);
        __builtin_amdgcn_s_setprio(0);
    }

    #pragma unroll
    for (int m = 0; m < 8; m++)
        #pragma unroll
        for (int n = 0; n < 4; n++)
            #pragma unroll
            for (int r = 0; r < 4; r++){
                int row = bm + wr*128 + m*16 + fq*4 + r;
                int col = bn + wc*64 + n*16 + fr;
                if (col < Ncols){
                    float v = acc[m][n][r];
                    if (OUT_BF16) ((u16*)Cp)[(size_t)row*Ncols + col] = f2bf(v);
                    else          ((float*)Cp)[(size_t)row*Ncols + col] = v;
                }
            }
}

// ---------------------------------------------------------------------------
// Vpack[h][ptile][d=144][key&31] = v[node][h*144+d] ; dense 9KB per KV tile.
// ---------------------------------------------------------------------------
__global__ __launch_bounds__(256) void pack_v(const u16* __restrict__ qkv,
                                              u16* __restrict__ Vpack,
                                              const int* __restrict__ batch,
                                              const int* __restrict__ meta,
                                              int PT){
    __shared__ u16 tile[32][33];
    int nt0 = blockIdx.x*32, dt0 = blockIdx.y*32, h = blockIdx.z;
    int tx = threadIdx.x & 31, ty = threadIdx.x >> 5;
    #pragma unroll
    for (int yy = ty; yy < 32; yy += 8){
        int node = nt0+yy, d = dt0+tx;
        tile[yy][tx] = (d < 144) ? qkv[(size_t)node*QKV_DIM + 2*F_DIM + h*144 + d] : (u16)0;
    }
    __syncthreads();
    int node = nt0 + tx;
    int g = batch[node];
    int col = meta[20+g] + (node - meta[1+g]);
    int pt = col >> 5, cl = col & 31;
    #pragma unroll
    for (int yy = ty; yy < 32; yy += 8){
        int d = dt0+yy;
        if (d < 144) Vpack[(((size_t)h*PT + pt)*144 + d)*32 + cl] = tile[tx][yy];
    }
}

// ---------------------------------------------------------------------------
// Flash attention: KVBLK=32, block = 4 waves = 4 q-tiles of one (graph,head).
// 38KB LDS -> 3 blocks/CU. No-max softmax, cvt_pk P-pack, setprio,
// reg-double-buffered bias (coalesced b128 from permuted table).
// ---------------------------------------------------------------------------
__global__ __launch_bounds__(256) void attn_kernel(
        const u16* __restrict__ qkv, const u16* __restrict__ Vpack,
        const u16* __restrict__ biasP, u16* __restrict__ attn_out,
        const int* __restrict__ meta, int PT){
    __shared__ u16 sK[2][4864];   // 32 rows x 304B (19 chunks, pad dup)
    __shared__ u16 sV[2][4608];   // [144][32] chunk-XOR swizzled
    const int h = blockIdx.x & 7, t4 = blockIdx.x >> 3;
    if (t4 >= meta[0]) return;
    const int g    = meta[64 + t4];
    const int q4   = meta[64 + MAX4 + t4];
    const int goff = meta[1+g], gend = meta[2+g];
    const int ng   = gend - goff;
    const int ntg  = (ng + 31) >> 5;
    const int pst  = meta[20+g];
    const int boffg= meta[40+g];

    const int tid = threadIdx.x;
    const int w = tid >> 6, lane = tid & 63;
    const int li = lane & 31, hi = lane >> 5;
    const int qt = q4*4 + w;
    const int qbase = goff + qt*32;
    const int qtP = (qt < ntg) ? qt : (ntg - 1);

    int kOff[3];
    #pragma unroll
    for (int p = 0; p < 3; p++){
        int idx = p*256 + tid;
        if (idx > 607) idx = 607;
        int row = idx/19, c = idx - row*19;
        if (c == 18) c = 0;
        kOff[p] = row*QKV_DIM + c*8;
    }
    const u16* kBase = qkv + (size_t)goff*QKV_DIM + F_DIM + h*144;
    int vOff[3];
    #pragma unroll
    for (int p = 0; p < 3; p++){
        int idx = p*256 + tid;
        if (idx > 575) idx = 575;
        int d = idx >> 2, c = idx & 3;
        vOff[p] = d*32 + ((c ^ (d & 3)) << 3);   // pre-swizzled src
    }
    const u16* vBase = Vpack + ((size_t)h*PT + (pst >> 5))*4608;
    const u16* bBase = biasP + ((size_t)boffg + (size_t)qtP*ntg)*8192 + h*1024 + li*32 + hi*16;

    int qnode = qbase + li; if (qnode >= gend) qnode = gend - 1;
    const u16* qrow = qkv + (size_t)qnode*QKV_DIM + h*144;
    bf16x8 qf[9];
    #pragma unroll
    for (int kk = 0; kk < 9; kk++) qf[kk] = *(const bf16x8*)(qrow + kk*16 + hi*8);

    int jlr[16];
    #pragma unroll
    for (int r = 0; r < 16; r++) jlr[r] = (r & 3) + ((r >> 2) << 3) + (hi << 2);

    float lrun = 0.f;
    f32x16 O[5];
    #pragma unroll
    for (int dt = 0; dt < 5; dt++)
        #pragma unroll
        for (int e = 0; e < 16; e++) O[dt][e] = 0.f;

    u32x4 bA0, bA1, bN0, bN1;
    bA0 = *(const u32x4*)bBase;
    bA1 = *(const u32x4*)(bBase + 8);
    {
        gload16(kBase + kOff[0], &sK[0][tid*8]);
        gload16(kBase + kOff[1], &sK[0][(256+tid)*8]);
        if (tid < 96) gload16(kBase + kOff[2], &sK[0][(512+tid)*8]);
        gload16(vBase + vOff[0], &sV[0][tid*8]);
        gload16(vBase + vOff[1], &sV[0][(256+tid)*8]);
        if (tid < 64) gload16(vBase + vOff[2], &sV[0][(512+tid)*8]);
    }
    __syncthreads();

    #pragma unroll 1
    for (int t = 0; t < ntg; t++){
        const int cur = t & 1;
        int tn = (t+1 < ntg) ? t+1 : ntg-1;
        bN0 = *(const u32x4*)(bBase + (size_t)tn*8192);
        bN1 = *(const u32x4*)(bBase + (size_t)tn*8192 + 8);
        __builtin_amdgcn_sched_barrier(0);
        if (t+1 < ntg){
            const u16* kb = kBase + (size_t)(t+1)*32*QKV_DIM;
            const u16* vb = vBase + (size_t)(t+1)*4608;
            gload16(kb + kOff[0], &sK[cur^1][tid*8]);
            gload16(kb + kOff[1], &sK[cur^1][(256+tid)*8]);
            if (tid < 96) gload16(kb + kOff[2], &sK[cur^1][(512+tid)*8]);
            gload16(vb + vOff[0], &sV[cur^1][tid*8]);
            gload16(vb + vOff[1], &sV[cur^1][(256+tid)*8]);
            if (tid < 64) gload16(vb + vOff[2], &sV[cur^1][(512+tid)*8]);
        }

        const u16* sKc = &sK[cur][0];
        f32x16 sacc;
        #pragma unroll
        for (int e = 0; e < 16; e++) sacc[e] = 0.f;
        __builtin_amdgcn_s_setprio(1);
        #pragma unroll
        for (int kk = 0; kk < 9; kk++){
            bf16x8 kf = *(const bf16x8*)(sKc + li*152 + kk*16 + hi*8);
            sacc = __builtin_amdgcn_mfma_f32_32x32x16_bf16(kf, qf[kk], sacc, 0, 0, 0);
        }
        __builtin_amdgcn_s_setprio(0);

        float bfv[16];
        #pragma unroll
        for (int q = 0; q < 4; q++){
            bfv[2*q]     = __builtin_bit_cast(float, bA0[q] << 16);
            bfv[2*q+1]   = __builtin_bit_cast(float, bA0[q] & 0xffff0000u);
            bfv[8+2*q]   = __builtin_bit_cast(float, bA1[q] << 16);
            bfv[8+2*q+1] = __builtin_bit_cast(float, bA1[q] & 0xffff0000u);
        }

        const int j0 = t*32;
        float p[16];
        float psum = 0.f;
        if (j0 + 32 <= ng){
            #pragma unroll
            for (int r = 0; r < 16; r++){
                float s_ = fminf(fmaf(sacc[r], KSC, bfv[r]), 86.f);
                p[r] = exp2f(s_); psum += p[r];
            }
        } else {
            #pragma unroll
            for (int r = 0; r < 16; r++){
                float s_ = fminf(fmaf(sacc[r], KSC, bfv[r]), 86.f);
                p[r] = (j0 + jlr[r] < ng) ? exp2f(s_) : 0.f;
                psum += p[r];
            }
        }
        psum += __shfl_xor(psum, 32);
        lrun += psum;

        u32 cpk[8], opk[8];
        #pragma unroll
        for (int q = 0; q < 8; q++) cpk[q] = cvtpk(p[2*q], p[2*q+1]);
        #pragma unroll
        for (int q = 0; q < 8; q++) opk[q] = (u32)__shfl_xor((int)cpk[q], 32);
        u32x4 a0, a1;
        if (hi == 0){
            a0[0]=cpk[0]; a0[1]=cpk[1]; a0[2]=opk[0]; a0[3]=opk[1];
            a1[0]=cpk[4]; a1[1]=cpk[5]; a1[2]=opk[4]; a1[3]=opk[5];
        } else {
            a0[0]=opk[2]; a0[1]=opk[3]; a0[2]=cpk[2]; a0[3]=cpk[3];
            a1[0]=opk[6]; a1[1]=opk[7]; a1[2]=cpk[6]; a1[3]=cpk[7];
        }
        bf16x8 paf0 = __builtin_bit_cast(bf16x8, a0);
        bf16x8 paf1 = __builtin_bit_cast(bf16x8, a1);

        const u16* sVc = &sV[cur][0];
        __builtin_amdgcn_s_setprio(1);
        #pragma unroll
        for (int dt = 0; dt < 5; dt++){
            int d = dt*32 + li;
            int dc = (d > 143) ? 143 : d;
            int swzlo = ((hi     ^ (dc & 3)) << 3);
            int swzhi = (((2+hi) ^ (dc & 3)) << 3);
            bf16x8 v0 = *(const bf16x8*)(sVc + dc*32 + swzlo);
            bf16x8 v1 = *(const bf16x8*)(sVc + dc*32 + swzhi);
            O[dt] = __builtin_amdgcn_mfma_f32_32x32x16_bf16(paf0, v0, O[dt], 0, 0, 0);
            O[dt] = __builtin_amdgcn_mfma_f32_32x32x16_bf16(paf1, v1, O[dt], 0, 0, 0);
        }
        __builtin_amdgcn_s_setprio(0);

        bA0 = bN0; bA1 = bN1;
        __syncthreads();
    }

    if (qt < ntg){
        float lr[16];
        #pragma unroll
        for (int r = 0; r < 16; r++) lr[r] = 1.0f / __shfl(lrun, jlr[r]);
        #pragma unroll
        for (int dt = 0; dt < 5; dt++){
            int d = dt*32 + li;
            if (d < 144){
                #pragma unroll
                for (int r = 0; r < 16; r++){
                    int qi = jlr[r];
                    if (qt*32 + qi < ng)
                        attn_out[(size_t)(qbase + qi)*F_DIM + h*144 + d] = f2bf(O[dt][r]*lr[r]);
                }
            }
        }
    }
}

// ---------------------------------------------------------------------------
// y = LayerNorm(x + out) * gamma + beta  (in-place over d_out), float4.
// ---------------------------------------------------------------------------
__global__ __launch_bounds__(256) void ln_kernel(const float* __restrict__ x,
                                                 float* __restrict__ io,
                                                 const float* __restrict__ gamma,
                                                 const float* __restrict__ beta){
    const int node = blockIdx.x;
    const float4* xr = (const float4*)(x  + (size_t)node*F_DIM);
    float4* yr       = (float4*)(io + (size_t)node*F_DIM);
    const int t = threadIdx.x;
    float4 h0, h1;
    float s = 0.f, ss = 0.f;
    {
        float4 a = xr[t], v = yr[t];
        h0.x = a.x+v.x; h0.y = a.y+v.y; h0.z = a.z+v.z; h0.w = a.w+v.w;
        s  += h0.x + h0.y + h0.z + h0.w;
        ss += h0.x*h0.x + h0.y*h0.y + h0.z*h0.z + h0.w*h0.w;
    }
    if (t < 32){
        float4 a = xr[256+t], v = yr[256+t];
        h1.x = a.x+v.x; h1.y = a.y+v.y; h1.z = a.z+v.z; h1.w = a.w+v.w;
        s  += h1.x + h1.y + h1.z + h1.w;
        ss += h1.x*h1.x + h1.y*h1.y + h1.z*h1.z + h1.w*h1.w;
    }
    #pragma unroll
    for (int o = 32; o > 0; o >>= 1){ s += __shfl_down(s, o); ss += __shfl_down(ss, o); }
    __shared__ float rs[4], rss[4];
    __shared__ float smu, srstd;
    if ((t & 63) == 0){ rs[t>>6] = s; rss[t>>6] = ss; }
    __syncthreads();
    if (t == 0){
        float S  = rs[0]+rs[1]+rs[2]+rs[3];
        float SS = rss[0]+rss[1]+rss[2]+rss[3];
        float mu = S * (1.f/F_DIM);
        float var = SS * (1.f/F_DIM) - mu*mu;
        smu = mu; srstd = rsqrtf(var + 1e-5f);
    }
    __syncthreads();
    float mu = smu, rstd = srstd;
    {
        float4 gv = ((const float4*)gamma)[t];
        float4 bv = ((const float4*)beta)[t];
        float4 o;
        o.x = (h0.x-mu)*rstd*gv.x + bv.x;
        o.y = (h0.y-mu)*rstd*gv.y + bv.y;
        o.z = (h0.z-mu)*rstd*gv.z + bv.z;
        o.w = (h0.w-mu)*rstd*gv.w + bv.w;
        yr[t] = o;
    }
    if (t < 32){
        float4 gv = ((const float4*)gamma)[256+t];
        float4 bv = ((const float4*)beta)[256+t];
        float4 o;
        o.x = (h1.x-mu)*rstd*gv.x + bv.x;
        o.y = (h1.y-mu)*rstd*gv.y + bv.y;
        o.z = (h1.z-mu)*rstd*gv.z + bv.z;
        o.w = (h1.w-mu)*rstd*gv.w + bv.w;
        yr[256+t] = o;
    }
}

// ---------------------------------------------------------------------------
extern "C" void kernel_launch(void* const* d_in, const int* in_sizes, int n_in,
                              void* d_out, int out_size, void* d_ws, size_t ws_size,
                              hipStream_t stream){
    const float* x     = (const float*)d_in[0];
    const float* pos   = (const float*)d_in[1];
    const float* Wqkv  = (const float*)d_in[2];
    const float* Wout  = (const float*)d_in[3];
    const float* rfreq = (const float*)d_in[4];
    const float* Wrope = (const float*)d_in[5];
    const float* gamma = (const float*)d_in[6];
    const float* beta  = (const float*)d_in[7];
    const int*   batch = (const int*)d_in[8];

    const int N  = in_sizes[0] / F_DIM;     // 8192
    const int PN = N + 512;                 // padded columns
    const int PT = PN / 32;                 // padded tiles

    char* ws = (char*)d_ws;
    size_t off = 0;
    auto alloc = [&](size_t b){ size_t o = off; off += (b + 255) & ~(size_t)255; return o; };
    int* meta   = (int*)(ws + alloc((size_t)(64 + 2*MAX4 + 64)*sizeof(int)));
    u16* xb     = (u16*)(ws + alloc((size_t)N*F_DIM*2));        // reused as attn_out
    u16* wqkvT  = (u16*)(ws + alloc((size_t)QKV_DIM*F_DIM*2));
    u16* woutT  = (u16*)(ws + alloc((size_t)F_DIM*F_DIM*2));
    u16* qkv    = (u16*)(ws + alloc((size_t)N*QKV_DIM*2));
    u16* Vpack  = (u16*)(ws + alloc((size_t)8*PT*144*32*2));
    u16* biasb  = (u16*)(ws + off);         // rest of workspace: bias blocks
    (void)ws_size; (void)n_in; (void)out_size;

    const int n4 = N*F_DIM/4;               // 2359296 = 1152*2048 exactly
    hipLaunchKernelGGL(prep_kernel, dim3(BIAS_BLKS + 1152 + 1296 + 1), dim3(256), 0, stream,
                       x, xb, n4, Wqkv, wqkvT, Wout, woutT,
                       pos, rfreq, Wrope, biasb, batch, meta, N);
    hipLaunchKernelGGL((gemm256<true>), dim3((N/256)*((QKV_DIM+255)/256)), dim3(512), 0, stream,
                       xb, wqkvT, (void*)qkv, N, QKV_DIM, F_DIM);
    hipLaunchKernelGGL(pack_v, dim3(N/32, 5, 8), dim3(256), 0, stream,
                       qkv, Vpack, batch, meta, PT);
    hipLaunchKernelGGL(attn_kernel, dim3(MAX4*8), dim3(256), 0, stream,
                       qkv, Vpack, biasb, xb, meta, PT);
    hipLaunchKernelGGL((gemm256<false>), dim3((N/256)*((F_DIM+255)/256)), dim3(512), 0, stream,
                       xb, woutT, d_out, N, F_DIM, F_DIM);
    hipLaunchKernelGGL(ln_kernel, dim3(N), dim3(256), 0, stream,
                       x, (float*)d_out, gamma, beta);
}